// Round 2
// baseline (3641.872 us; speedup 1.0000x reference)
//
#include <hip/hip_runtime.h>
#include <stdint.h>

#define NB 256
#define NBATCH 128
#define HID 64
#define MAXEV 5
#define MAXSTEPS 256
#define NT 43          /* 43*6 = 258 >= 256 */
#define NTILES 946     /* 43*44/2 */
#define W2S 65         /* padded LDS stride for W2 rows */
#define CAND_MAX 6144  /* big list (multi-step) */
#define T_MAX 2048     /* tight list (per-step) */
#define CMARGIN 1.5f   /* gap-shrink budget of big list */
#define TMARGIN 0.9f   /* gap-shrink budget of tight list (per step) */

__device__ __forceinline__ float bf2f(unsigned short u) {
    return __uint_as_float(((unsigned)u) << 16);
}
__device__ __forceinline__ unsigned short f2bf(float f) {
    unsigned u = __float_as_uint(f);
    u += 0x7FFFu + ((u >> 16) & 1u);
    return (unsigned short)(u >> 16);
}
__device__ __forceinline__ float rdin(const void* p, int idx, int bf) {
    return bf ? bf2f(((const unsigned short*)p)[idx]) : ((const float*)p)[idx];
}
__device__ __forceinline__ float silu_f(float x) {
    float s = __fdiv_rn(1.0f, __fadd_rn(1.0f, expf(-x)));
    return __fmul_rn(x, s);
}
__device__ __forceinline__ void lds_fence() {   // in-wave LDS round-trip ordering
    __builtin_amdgcn_wave_barrier();
    __threadfence_block();
    __builtin_amdgcn_wave_barrier();
}

// ---- DPP wave reductions (VALU pipe, no LDS traffic; exact min/max) ----
template<int CTRL>
__device__ __forceinline__ unsigned long long dpp_min_u64_step(unsigned long long k) {
    unsigned lo = (unsigned)k, hi = (unsigned)(k >> 32);
    unsigned nlo = (unsigned)__builtin_amdgcn_update_dpp(-1, (int)lo, CTRL, 0xF, 0xF, false);
    unsigned nhi = (unsigned)__builtin_amdgcn_update_dpp(-1, (int)hi, CTRL, 0xF, 0xF, false);
    unsigned long long nk = (((unsigned long long)nhi) << 32) | (unsigned long long)nlo;
    return nk < k ? nk : k;
}
__device__ __forceinline__ unsigned long long wave_min_u64(unsigned long long k) {
    k = dpp_min_u64_step<0x111>(k);   // row_shr:1
    k = dpp_min_u64_step<0x112>(k);   // row_shr:2
    k = dpp_min_u64_step<0x114>(k);   // row_shr:4
    k = dpp_min_u64_step<0x118>(k);   // row_shr:8
    k = dpp_min_u64_step<0x142>(k);   // row_bcast:15
    k = dpp_min_u64_step<0x143>(k);   // row_bcast:31  -> lane 63 has wave min
    unsigned lo = (unsigned)__builtin_amdgcn_readlane((int)(unsigned)k, 63);
    unsigned hi = (unsigned)__builtin_amdgcn_readlane((int)(unsigned)(k >> 32), 63);
    return (((unsigned long long)hi) << 32) | (unsigned long long)lo;
}
template<int CTRL>
__device__ __forceinline__ float dpp_max_f32_step(float x) {
    int nx = __builtin_amdgcn_update_dpp(0, __float_as_int(x), CTRL, 0xF, 0xF, false);
    return fmaxf(x, __int_as_float(nx));   // values >= 0, identity 0 safe
}
__device__ __forceinline__ float wave_max_f32(float x) {
    x = dpp_max_f32_step<0x111>(x);
    x = dpp_max_f32_step<0x112>(x);
    x = dpp_max_f32_step<0x114>(x);
    x = dpp_max_f32_step<0x118>(x);
    x = dpp_max_f32_step<0x142>(x);
    x = dpp_max_f32_step<0x143>(x);
    return __int_as_float(__builtin_amdgcn_readlane(__float_as_int(x), 63));
}

// ---- wave-aggregated LDS list append (1 atomic per wave per ballot) ----
__device__ __forceinline__ void append_agg(unsigned* list, int* counter, int cap, unsigned val) {
    unsigned long long m = __ballot(1);
    int lane = (int)(threadIdx.x & 63);
    int ldr = (int)__builtin_ctzll(m);
    int pfx = (int)__builtin_popcountll(m & ((1ull << lane) - 1ull));
    int base = 0;
    if (lane == ldr) base = atomicAdd(counter, (int)__builtin_popcountll(m));
    base = __builtin_amdgcn_readfirstlane(base);
    int idx = base + pfx;
    if (idx < cap) list[idx] = val;
}

__device__ void load_weights(float* w1, float* b1s, float* w2, float* b2s, float* w3, float* b3s,
                             const void* W1, const void* B1, const void* W2, const void* B2,
                             const void* W3, const void* B3, int bf, int tid, int nthr) {
    for (int k = tid; k < HID * 2; k += nthr) w1[k] = rdin(W1, k, bf);
    for (int k = tid; k < HID; k += nthr) {
        b1s[k] = rdin(B1, k, bf);
        b2s[k] = rdin(B2, k, bf);
        w3[k]  = rdin(W3, k, bf);
    }
    for (int k = tid; k < HID * HID; k += nthr) {
        int m = k >> 6, c = k & 63;
        w2[m * W2S + c] = rdin(W2, k, bf);
    }
    if (tid == 0) b3s[0] = rdin(B3, 0, bf);
}

// ---------------- dtype sniffer ----------------
__global__ void sniff_kernel(const unsigned short* st, int* ws) {
    __shared__ int ev;
    if (threadIdx.x == 0) ev = 0;
    __syncthreads();
    unsigned short u = st[threadIdx.x];
    int e = (u >> 7) & 0xFF;
    if (e >= 0x85) atomicOr(&ev, 1);
    __syncthreads();
    if (threadIdx.x == 0) ws[0] = ev ? 0 : 1;   // 1 = bf16, 0 = fp32
}

// ---------------- output row 0 = initial state (bit copy) ----------------
__global__ void row0_kernel(const void* in, void* out, const int* ws) {
    int idx = blockIdx.x * blockDim.x + threadIdx.x;
    if (ws[0]) ((unsigned short*)out)[idx] = ((const unsigned short*)in)[idx];
    else       ((float*)out)[idx] = ((const float*)in)[idx];
}

// ------- redundant-producer, wave0-decision, two-tier candidate event loop -------
__global__ __launch_bounds__(1024, 1) void sim_kernel(
    const void* in_state, const void* in_rad,
    const void* inW1, const void* inB1, const void* inW2, const void* inB2,
    const void* inW3, const void* inB3, const void* in_dt, const int* in_nsteps,
    void* out, const int* ws) {
    __shared__ float4 ps0[NB];          // batch-0 sim (decision state)
    __shared__ float4 psb[NB];          // own-batch sim
    __shared__ float rad[NB];
    __shared__ float w1[HID * 2], b1s[HID], w2[HID * W2S], b2s[HID], w3s[HID], b3s[1];
    __shared__ float sc0[132], scb[132];      // [4..67] h1, [68..131] h2
    __shared__ unsigned long long redP[16], redW[16];
    __shared__ float redF[4];
    __shared__ unsigned cand[CAND_MAX];       // big list (valid across steps)
    __shared__ unsigned cand2[T_MAX];         // tight list (rebuilt at e==0 each step)
    __shared__ int candN, candN2;
    __shared__ int dI[4];
    __shared__ float dF[4];
    __shared__ int candF;              // big list invalid (fallback: full scan)
    __shared__ int candFt;             // tight list invalid (fallback: big scan)
    __shared__ int rebF;               // rebuild big list at next step's e==0

    int tid = threadIdx.x;
    int b = blockIdx.x;
    int bf = ws[0];

    if (tid < NB) {
        int base0 = tid * 4;
        float4 P;
        P.x = rdin(in_state, base0 + 0, bf);
        P.y = rdin(in_state, base0 + 1, bf);
        P.z = rdin(in_state, base0 + 2, bf);
        P.w = rdin(in_state, base0 + 3, bf);
        ps0[tid] = P;
        int baseb = (b * NB + tid) * 4;
        float4 Q;
        Q.x = rdin(in_state, baseb + 0, bf);
        Q.y = rdin(in_state, baseb + 1, bf);
        Q.z = rdin(in_state, baseb + 2, bf);
        Q.w = rdin(in_state, baseb + 3, bf);
        psb[tid] = Q;
        rad[tid] = rdin(in_rad, tid, bf);
        float m2 = P.z * P.z + P.w * P.w;
        m2 = wave_max_f32(m2);
        if ((tid & 63) == 0) redF[tid >> 6] = m2;
    }
    load_weights(w1, b1s, w2, b2s, w3s, b3s, inW1, inB1, inW2, inB2, inW3, inB3, bf, tid, 1024);
    if (tid == 0) { candN = 0; candN2 = 0; candF = 0; candFt = 0; rebF = 1; }

    float dtv = rdin(in_dt, 0, bf);
    int NS = in_nsteps[0]; if (NS > MAXSTEPS) NS = MAXSTEPS; if (NS < 0) NS = 0;

    // static tile assignment (one 6x6 tile per thread, tids 0..945)
    int myI0 = -1, myJ0 = 0;
    if (tid < NTILES) {
        int rem = tid, r = 0;
        while (rem >= NT - r) { rem -= NT - r; r++; }
        myI0 = r * 6; myJ0 = (r + rem) * 6;
    }
    __syncthreads();
    float rsum = __fadd_rn(rad[0], rad[0]);        // radii uniform

    float thB = __fadd_rn(__fadd_rn(rsum, 0.05f), CMARGIN);
    float th2B = __fmul_rn(thB, thB);
    float thT = __fadd_rn(__fadd_rn(rsum, 0.05f), TMARGIN);
    float th2T = __fmul_rn(thT, thT);

    int nc = 0, ncT = 0;
    bool candOvf = false, tOvf = false;
    // wave-0 persistent budget state
    float used = 1e30f, usedT = 0.0f, vcap = 0.0f;

    for (int s = 0; s < NS; s++) {
        int rebuild = rebF;
        float t_s = __fmul_rn((float)s, dtv);
        float t_e = __fadd_rn(t_s, dtv);
        float t_c = t_s;
        if (tid < 64) {
            if (rebuild) {
                vcap = sqrtf(fmaxf(fmaxf(redF[0], redF[1]), fmaxf(redF[2], redF[3])));
                used = 0.0f;
            }
            // pre-charge this step's worst-case motion (bit-identical to rebF check)
            float pre = __fmul_rn(__fmul_rn(2.0f, dtv), vcap);
            used = __fadd_rn(used, pre);
            usedT = pre;
            if (tid == 0) { if (rebuild) candF = 0; candFt = 0; }
        }

        for (int e = 0; e < MAXEV; e++) {
            // ---------- detect phase (all 1024 threads) ----------
            unsigned long long kP = ~0ull, kW = ~0ull;
            int mode;                               // 0=tight 1=big 2=full
            if (e == 0) mode = rebuild ? 2 : 1;
            else       mode = candF ? 2 : (candFt ? 1 : 0);
            bool apT = (e == 0);                    // build tight list this scan

            if (mode == 2) {
                bool apB = apT;                     // mode2 @ e==0 <=> rebuild
                if (myI0 >= 0) {
                    float4 Pi[6], Pj[6];
                    #pragma unroll
                    for (int a = 0; a < 6; a++) {
                        int ii = myI0 + a; ii = ii < NB ? ii : NB - 1;
                        int jj = myJ0 + a; jj = jj < NB ? jj : NB - 1;
                        Pi[a] = ps0[ii]; Pj[a] = ps0[jj];
                    }
                    #pragma unroll
                    for (int a = 0; a < 6; a++) {
                        int i = myI0 + a;
                        #pragma unroll
                        for (int bb = 0; bb < 6; bb++) {
                            int j = myJ0 + bb;
                            bool ok = (i < NB) && (j < NB) && (j > i);
                            float dx = __fsub_rn(Pj[bb].x, Pi[a].x);
                            float dy = __fsub_rn(Pj[bb].y, Pi[a].y);
                            float d2 = __fadd_rn(__fmul_rn(dx, dx), __fmul_rn(dy, dy));
                            unsigned id = (unsigned)((i << 8) | j);
                            bool nearT = ok && (d2 < th2T);
                            if (nearT) {
                                // appr-test only for pairs that can matter (gap<=0.05 => d2<0.0625<th2T)
                                float p1 = __fmul_rn(__fsub_rn(Pj[bb].z, Pi[a].z), dx);
                                float p2 = __fmul_rn(__fsub_rn(Pj[bb].w, Pi[a].w), dy);
                                float dot = __fadd_rn(p1, p2);
                                float mag = __fadd_rn(fabsf(p1), fabsf(p2));
                                bool appr;
                                if (fabsf(dot) < __fmul_rn(1e-5f, mag)) {
                                    float dist = __fsqrt_rn(d2);
                                    float den = __fadd_rn(dist, 1e-8f);
                                    float ab = __fadd_rn(
                                        __fmul_rn(__fsub_rn(Pj[bb].z, Pi[a].z), __fdiv_rn(dx, den)),
                                        __fmul_rn(__fsub_rn(Pj[bb].w, Pi[a].w), __fdiv_rn(dy, den)));
                                    appr = ab < 0.0f;
                                } else {
                                    appr = dot < 0.0f;
                                }
                                if (appr) {
                                    unsigned long long key =
                                        (((unsigned long long)__float_as_uint(d2)) << 16) | id;
                                    kP = key < kP ? key : kP;
                                }
                            }
                            if (apB) {
                                if (nearT) append_agg(cand2, &candN2, T_MAX, id);
                                if (ok && d2 < th2B) append_agg(cand, &candN, CAND_MAX, id);
                            }
                        }
                    }
                }
            } else {
                const unsigned* src = (mode == 1) ? cand : cand2;
                int n = (mode == 1) ? nc : ncT;
                bool apT2 = apT && (mode == 1);     // e==0 non-rebuild: build tight from big
                for (int c = tid; c < n; c += 1024) {
                    unsigned id = src[c];
                    int i = (int)(id >> 8), j = (int)(id & 255u);
                    float4 A = ps0[i], B = ps0[j];
                    float dx = __fsub_rn(B.x, A.x), dy = __fsub_rn(B.y, A.y);
                    float d2 = __fadd_rn(__fmul_rn(dx, dx), __fmul_rn(dy, dy));
                    if (d2 < th2T) {
                        float p1 = __fmul_rn(__fsub_rn(B.z, A.z), dx);
                        float p2 = __fmul_rn(__fsub_rn(B.w, A.w), dy);
                        float dot = __fadd_rn(p1, p2);
                        float mag = __fadd_rn(fabsf(p1), fabsf(p2));
                        bool appr;
                        if (fabsf(dot) < __fmul_rn(1e-5f, mag)) {
                            float dist = __fsqrt_rn(d2);
                            float den = __fadd_rn(dist, 1e-8f);
                            float ab = __fadd_rn(
                                __fmul_rn(__fsub_rn(B.z, A.z), __fdiv_rn(dx, den)),
                                __fmul_rn(__fsub_rn(B.w, A.w), __fdiv_rn(dy, den)));
                            appr = ab < 0.0f;
                        } else {
                            appr = dot < 0.0f;
                        }
                        if (appr) {
                            unsigned long long key =
                                (((unsigned long long)__float_as_uint(d2)) << 16) | id;
                            kP = key < kP ? key : kP;
                        }
                        if (apT2) append_agg(cand2, &candN2, T_MAX, id);
                    }
                }
            }
            {   // wall candidate: exactly one per thread (tid = ball*4+w)
                int ball = tid >> 2, w = tid & 3;
                float4 P = ps0[ball]; float r = rad[ball];
                float g; bool valid;
                if (w == 0)      { g = __fsub_rn(P.x, r); valid = P.z < 0.0f; }
                else if (w == 1) { g = __fsub_rn(__fsub_rn(10.0f, P.x), r); valid = P.z > 0.0f; }
                else if (w == 2) { g = __fsub_rn(P.y, r); valid = P.w < 0.0f; }
                else             { g = __fsub_rn(__fsub_rn(10.0f, P.y), r); valid = P.w > 0.0f; }
                if (valid) {
                    unsigned gb = __float_as_uint(g);
                    unsigned m = (unsigned)(((int)gb) >> 31) | 0x80000000u;
                    unsigned sb = gb ^ m;
                    unsigned long long key = (((unsigned long long)sb) << 16) | (unsigned)tid;
                    kW = key < kW ? key : kW;
                }
            }
            kP = wave_min_u64(kP);
            kW = wave_min_u64(kW);
            if ((tid & 63) == 0) { redP[tid >> 6] = kP; redW[tid >> 6] = kW; }
            __syncthreads();                                     // B1

            if (e == 0) {
                if (rebuild) {
                    int ct = candN;
                    candOvf = ct > CAND_MAX;
                    nc = candOvf ? CAND_MAX : ct;
                }
                int ct2 = candN2;
                tOvf = ct2 > T_MAX;
                ncT = tOvf ? T_MAX : ct2;
            }

            // ---------- decision: wave 0 only; sim0 geometry kept in registers ----------
            float g_nx = 0, g_ny = 0, g_dist = 0, g_app = 0;
            float4 gA, gB;
            if (tid < 64) {
                unsigned long long mP = redP[0], mW = redW[0];
                #pragma unroll
                for (int q = 1; q < 16; q++) {
                    mP = redP[q] < mP ? redP[q] : mP;
                    mW = redW[q] < mW ? redW[q] : mW;
                }
                float gball = 1e30f; int pi = 0, pj = 1;
                if (mP != ~0ull) {
                    unsigned id = (unsigned)(mP & 0xFFFFull);
                    pi = id >> 8; pj = id & 255u;
                    float d2 = __uint_as_float((unsigned)(mP >> 16));
                    gball = __fsub_rn(__fsqrt_rn(d2), rsum);
                }
                float gwall = 1e30f; int wb = 0, ww = 0;
                if (mW != ~0ull) {
                    unsigned id = (unsigned)(mW & 0xFFFFull);
                    wb = id >> 2; ww = id & 3u;
                    unsigned sb = (unsigned)(mW >> 16);
                    unsigned gb = (sb & 0x80000000u) ? (sb ^ 0x80000000u) : ~sb;
                    gwall = __uint_as_float(gb);
                }
                bool is_ball = gball <= gwall;
                float gap = is_ball ? gball : gwall;
                int code_ = 0; float dteB_ = 0.0f, tcn_ = t_c;
                if (!(gap > 0.05f)) {
                    float app;
                    if (is_ball) {
                        float4 A = ps0[pi], B = ps0[pj];
                        float dx = __fsub_rn(B.x, A.x), dy = __fsub_rn(B.y, A.y);
                        float nrm = __fsqrt_rn(__fadd_rn(__fmul_rn(dx, dx), __fmul_rn(dy, dy)));
                        float dvx = __fsub_rn(B.z, A.z), dvy = __fsub_rn(B.w, A.w);
                        app = -__fadd_rn(__fdiv_rn(__fmul_rn(dvx, dx), nrm),
                                         __fdiv_rn(__fmul_rn(dvy, dy), nrm));
                    } else {
                        float4 Wb = ps0[wb];
                        app = fabsf(fmaxf(Wb.z, Wb.w));
                    }
                    float t_ev = __fadd_rn(t_c, __fdiv_rn(gap, fmaxf(app, 1e-6f)));
                    if (gap <= 0.0f) {
                        code_ = is_ball ? 1 : 3;
                    } else if (app > 1e-6f && t_ev < t_e) {
                        code_ = is_ball ? 2 : 4;
                        dteB_ = (t_ev > __fadd_rn(t_c, 1e-10f)) ? __fsub_rn(t_ev, t_c) : 0.0f;
                        tcn_ = t_ev;
                    }
                }
                int ei_ = is_ball ? pi : wb;
                int ej_ = is_ball ? pj : ww;
                if (tid == 0) {
                    dI[0] = code_; dI[1] = ei_; dI[2] = ej_;
                    dF[0] = dteB_; dF[1] = tcn_;
                }
                if (code_ != 0 && code_ <= 2) {
                    float4 A = ps0[ei_], B = ps0[ej_];
                    if (code_ == 2) {
                        A.x = __fadd_rn(A.x, __fmul_rn(A.z, dteB_));
                        A.y = __fadd_rn(A.y, __fmul_rn(A.w, dteB_));
                        B.x = __fadd_rn(B.x, __fmul_rn(B.z, dteB_));
                        B.y = __fadd_rn(B.y, __fmul_rn(B.w, dteB_));
                    }
                    gA = A; gB = B;
                    float dx = __fsub_rn(B.x, A.x), dy = __fsub_rn(B.y, A.y);
                    float nrm = __fsqrt_rn(__fadd_rn(__fmul_rn(dx, dx), __fmul_rn(dy, dy)));
                    float dist = fmaxf(nrm, 1e-8f);
                    g_nx = __fdiv_rn(dx, dist); g_ny = __fdiv_rn(dy, dist);
                    g_dist = dist;
                    float dvx = __fsub_rn(B.z, A.z), dvy = __fsub_rn(B.w, A.w);
                    g_app = __fadd_rn(__fmul_rn(dvx, g_nx), __fmul_rn(dvy, g_ny));
                }
            }
            __syncthreads();                                     // B1b (publish)

            int code = dI[0];
            if (code == 0) break;
            int ei = dI[1], ejw = dI[2];
            float dteB = dF[0];
            t_c = dF[1];
            bool integ = (code == 2) || (code == 4);

            // ---------- apply phase P2 (one barrier at end) ----------
            if (code <= 2) {
                if (tid < 64) {
                    // wave 0: sim0 MLP from registers, in-wave LDS round-trips
                    float a = __fadd_rn(__fadd_rn(__fmul_rn(g_dist, w1[2 * tid]),
                                                  __fmul_rn(g_app, w1[2 * tid + 1])), b1s[tid]);
                    sc0[4 + tid] = silu_f(a);
                    lds_fence();
                    float acc = 0.0f;
                    const float* row = &w2[tid * W2S];
                    #pragma unroll 8
                    for (int k = 0; k < HID; k++) acc = __fadd_rn(acc, __fmul_rn(sc0[4 + k], row[k]));
                    acc = __fadd_rn(acc, b2s[tid]);
                    sc0[68 + tid] = silu_f(acc);
                    lds_fence();
                    float acc3 = 0.0f;
                    #pragma unroll 8
                    for (int k = 0; k < HID; k++)
                        acc3 = __fadd_rn(acc3, __fmul_rn(sc0[68 + k], w3s[k]));
                    float impv = __fadd_rn(acc3, b3s[0]);
                    float ix = __fmul_rn(impv, g_nx), iy = __fmul_rn(impv, g_ny);
                    float nAz = __fadd_rn(gA.z, ix),  nAw = __fadd_rn(gA.w, iy);
                    float nBz = __fadd_rn(gB.z, -ix), nBw = __fadd_rn(gB.w, -iy);
                    if (tid == 0) {
                        float4 outA; outA.x = gA.x; outA.y = gA.y; outA.z = nAz; outA.w = nAw;
                        float4 outB; outB.x = gB.x; outB.y = gB.y; outB.z = nBz; outB.w = nBw;
                        ps0[ei] = outA; ps0[ejw] = outB;
                    }
                    float s1 = sqrtf(nAz * nAz + nAw * nAw);
                    float s2 = sqrtf(nBz * nBz + nBw * nBw);
                    float nv = fmaxf(s1, s2);
                    float delta = __fmul_rn(__fmul_rn(2.0f, dtv),
                                            fmaxf(__fsub_rn(nv, vcap), 0.0f));
                    used = __fadd_rn(used, delta);
                    usedT = __fadd_rn(usedT, delta);
                    vcap = fmaxf(vcap, nv);
                    int nf  = (candOvf || (__fadd_rn(used, 1e-3f) > CMARGIN)) ? 1 : 0;
                    int nft = (tOvf || (__fadd_rn(usedT, 1e-3f) > TMARGIN)) ? 1 : 0;
                    if (tid == 0) { candF = nf; candFt = nft; }
                } else if (tid < 128) {
                    // wave 1: simb full apply (geometry + MLP), in-wave
                    int lane = tid - 64;
                    float4 A = psb[ei], B = psb[ejw];
                    if (integ) {
                        A.x = __fadd_rn(A.x, __fmul_rn(A.z, dteB));
                        A.y = __fadd_rn(A.y, __fmul_rn(A.w, dteB));
                        B.x = __fadd_rn(B.x, __fmul_rn(B.z, dteB));
                        B.y = __fadd_rn(B.y, __fmul_rn(B.w, dteB));
                    }
                    float dx = __fsub_rn(B.x, A.x), dy = __fsub_rn(B.y, A.y);
                    float nrm = __fsqrt_rn(__fadd_rn(__fmul_rn(dx, dx), __fmul_rn(dy, dy)));
                    float dist = fmaxf(nrm, 1e-8f);
                    float nx = __fdiv_rn(dx, dist), ny = __fdiv_rn(dy, dist);
                    float dvx = __fsub_rn(B.z, A.z), dvy = __fsub_rn(B.w, A.w);
                    float app2 = __fadd_rn(__fmul_rn(dvx, nx), __fmul_rn(dvy, ny));
                    float a = __fadd_rn(__fadd_rn(__fmul_rn(dist, w1[2 * lane]),
                                                  __fmul_rn(app2, w1[2 * lane + 1])), b1s[lane]);
                    scb[4 + lane] = silu_f(a);
                    lds_fence();
                    float acc = 0.0f;
                    const float* row = &w2[lane * W2S];
                    #pragma unroll 8
                    for (int k = 0; k < HID; k++) acc = __fadd_rn(acc, __fmul_rn(scb[4 + k], row[k]));
                    acc = __fadd_rn(acc, b2s[lane]);
                    scb[68 + lane] = silu_f(acc);
                    lds_fence();
                    float acc3 = 0.0f;
                    #pragma unroll 8
                    for (int k = 0; k < HID; k++)
                        acc3 = __fadd_rn(acc3, __fmul_rn(scb[68 + k], w3s[k]));
                    float impv = __fadd_rn(acc3, b3s[0]);
                    if (lane == 0) {
                        float ix = __fmul_rn(impv, nx), iy = __fmul_rn(impv, ny);
                        float4 outA; outA.x = A.x; outA.y = A.y;
                        outA.z = __fadd_rn(A.z, ix);  outA.w = __fadd_rn(A.w, iy);
                        float4 outB; outB.x = B.x; outB.y = B.y;
                        outB.z = __fadd_rn(B.z, -ix); outB.w = __fadd_rn(B.w, -iy);
                        psb[ei] = outA; psb[ejw] = outB;
                    }
                } else if (tid < 384) {
                    int t = tid - 128;
                    if (integ && t != ei && t != ejw) {
                        float4 P = ps0[t];
                        P.x = __fadd_rn(P.x, __fmul_rn(P.z, dteB));
                        P.y = __fadd_rn(P.y, __fmul_rn(P.w, dteB));
                        ps0[t] = P;
                    }
                } else if (tid < 640) {
                    int t = tid - 384;
                    if (integ && t != ei && t != ejw) {
                        float4 Q = psb[t];
                        Q.x = __fadd_rn(Q.x, __fmul_rn(Q.z, dteB));
                        Q.y = __fadd_rn(Q.y, __fmul_rn(Q.w, dteB));
                        psb[t] = Q;
                    }
                }
                __syncthreads();                                 // P2 end
            } else {
                // ---------- wall event ----------
                const float wnx[4] = {1.f, -1.f, 0.f, 0.f};
                const float wny[4] = {0.f, 0.f, 1.f, -1.f};
                const float wpv[4] = {0.f, -10.f, 0.f, -10.f};
                int w = ejw;
                if (tid < 64) {
                    float4 P = ps0[ei];
                    if (integ) {
                        P.x = __fadd_rn(P.x, __fmul_rn(P.z, dteB));
                        P.y = __fadd_rn(P.y, __fmul_rn(P.w, dteB));
                    }
                    float vn = __fadd_rn(__fmul_rn(P.z, wnx[w]), __fmul_rn(P.w, wny[w]));
                    float t2 = __fmul_rn(2.0f, vn);
                    float nvx = __fsub_rn(P.z, __fmul_rn(t2, wnx[w]));
                    float nvy = __fsub_rn(P.w, __fmul_rn(t2, wny[w]));
                    float pn = __fadd_rn(__fmul_rn(P.x, wnx[w]), __fmul_rn(P.y, wny[w]));
                    float pen = fmaxf(__fsub_rn(__fadd_rn(wpv[w], rad[ei]), pn), 0.0f);
                    float4 nP;
                    nP.x = __fadd_rn(P.x, __fmul_rn(pen, wnx[w]));
                    nP.y = __fadd_rn(P.y, __fmul_rn(pen, wny[w]));
                    nP.z = nvx; nP.w = nvy;
                    used = __fadd_rn(used, pen);
                    usedT = __fadd_rn(usedT, pen);
                    int nf  = (candOvf || (__fadd_rn(used, 1e-3f) > CMARGIN)) ? 1 : 0;
                    int nft = (tOvf || (__fadd_rn(usedT, 1e-3f) > TMARGIN)) ? 1 : 0;
                    if (tid == 0) { ps0[ei] = nP; candF = nf; candFt = nft; }
                } else if (tid < 128) {
                    if (tid == 64) {
                        float4 P = psb[ei];
                        if (integ) {
                            P.x = __fadd_rn(P.x, __fmul_rn(P.z, dteB));
                            P.y = __fadd_rn(P.y, __fmul_rn(P.w, dteB));
                        }
                        float vn = __fadd_rn(__fmul_rn(P.z, wnx[w]), __fmul_rn(P.w, wny[w]));
                        float t2 = __fmul_rn(2.0f, vn);
                        float nvx = __fsub_rn(P.z, __fmul_rn(t2, wnx[w]));
                        float nvy = __fsub_rn(P.w, __fmul_rn(t2, wny[w]));
                        float pn = __fadd_rn(__fmul_rn(P.x, wnx[w]), __fmul_rn(P.y, wny[w]));
                        float pen = fmaxf(__fsub_rn(__fadd_rn(wpv[w], rad[ei]), pn), 0.0f);
                        float4 nP;
                        nP.x = __fadd_rn(P.x, __fmul_rn(pen, wnx[w]));
                        nP.y = __fadd_rn(P.y, __fmul_rn(pen, wny[w]));
                        nP.z = nvx; nP.w = nvy;
                        psb[ei] = nP;
                    }
                } else if (tid < 384) {
                    int t = tid - 128;
                    if (integ && t != ei) {
                        float4 P = ps0[t];
                        P.x = __fadd_rn(P.x, __fmul_rn(P.z, dteB));
                        P.y = __fadd_rn(P.y, __fmul_rn(P.w, dteB));
                        ps0[t] = P;
                    }
                } else if (tid < 640) {
                    int t = tid - 384;
                    if (integ && t != ei) {
                        float4 Q = psb[t];
                        Q.x = __fadd_rn(Q.x, __fmul_rn(Q.z, dteB));
                        Q.y = __fadd_rn(Q.y, __fmul_rn(Q.w, dteB));
                        psb[t] = Q;
                    }
                }
                __syncthreads();                                 // P2 end
            }
        }

        // ---------- step end: final integrate + vmax + store (fused) ----------
        float fd = (t_e > __fadd_rn(t_c, 1e-10f)) ? __fsub_rn(t_e, t_c) : 0.0f;
        if (tid < NB) {
            float4 P = ps0[tid];
            P.x = __fadd_rn(P.x, __fmul_rn(P.z, fd));
            P.y = __fadd_rn(P.y, __fmul_rn(P.w, fd));
            ps0[tid] = P;
            float m2 = P.z * P.z + P.w * P.w;
            m2 = wave_max_f32(m2);
            if ((tid & 63) == 0) redF[tid >> 6] = m2;
            if (tid == 0) {
                candN = 0; candN2 = 0;
                // schedule rebuild iff next step's pre-charge would blow the budget
                // (bit-identical arithmetic to the step-start pre-charge)
                float usedNext = __fadd_rn(used, __fmul_rn(__fmul_rn(2.0f, dtv), vcap));
                rebF = (candOvf || (__fadd_rn(usedNext, 1e-3f) > CMARGIN)) ? 1 : 0;
            }
        } else if (tid < 2 * NB) {
            int t = tid - NB;
            float4 Q = psb[t];
            Q.x = __fadd_rn(Q.x, __fmul_rn(Q.z, fd));
            Q.y = __fadd_rn(Q.y, __fmul_rn(Q.w, fd));
            psb[t] = Q;
            long long base = ((long long)(s + 1) * NBATCH + b) * (NB * 4);
            if (bf) {
                ushort4 v;
                v.x = f2bf(Q.x); v.y = f2bf(Q.y); v.z = f2bf(Q.z); v.w = f2bf(Q.w);
                ((ushort4*)((unsigned short*)out + base))[t] = v;
            } else {
                ((float4*)((float*)out + base))[t] = Q;
            }
        }
        __syncthreads();
    }
}

extern "C" void kernel_launch(void* const* d_in, const int* in_sizes, int n_in,
                              void* d_out, int out_size, void* d_ws, size_t ws_size,
                              hipStream_t stream) {
    // inputs: 0 state, 1 radii, 2 W1, 3 b1, 4 W2, 5 b2, 6 W3, 7 b3, 8 dt, 9 n_steps
    int* ws = (int*)d_ws;
    sniff_kernel<<<1, 256, 0, stream>>>((const unsigned short*)d_in[0], ws);
    row0_kernel<<<(NBATCH * NB * 4) / 256, 256, 0, stream>>>(d_in[0], d_out, ws);
    sim_kernel<<<NBATCH, 1024, 0, stream>>>(
        d_in[0], d_in[1], d_in[2], d_in[3], d_in[4], d_in[5], d_in[6], d_in[7],
        d_in[8], (const int*)d_in[9], d_out, ws);
}

// Round 3
// 3317.323 us; speedup vs baseline: 1.0978x; 1.0978x over previous
//
#include <hip/hip_runtime.h>
#include <stdint.h>

#define NB 256
#define NBATCH 128
#define HID 64
#define MAXEV 5
#define MAXSTEPS 256
#define NT 43          /* 43*6 = 258 >= 256 */
#define NTILES 946     /* 43*44/2 */
#define W2S 65         /* padded LDS stride for W2 rows */
#define CAND_MAX 6144
#define CMARGIN 1.5f   /* total gap-shrink budget of candidate list */
#define NTHR 512
#define D2GATE 0.0626f /* pairs beyond this d2 cannot have gap <= 0.05 */

typedef unsigned long long u64;

__device__ __forceinline__ float bf2f(unsigned short u) {
    return __uint_as_float(((unsigned)u) << 16);
}
__device__ __forceinline__ unsigned short f2bf(float f) {
    unsigned u = __float_as_uint(f);
    u += 0x7FFFu + ((u >> 16) & 1u);
    return (unsigned short)(u >> 16);
}
__device__ __forceinline__ float rdin(const void* p, int idx, int bf) {
    return bf ? bf2f(((const unsigned short*)p)[idx]) : ((const float*)p)[idx];
}
__device__ __forceinline__ float silu_f(float x) {
    float s = __fdiv_rn(1.0f, __fadd_rn(1.0f, expf(-x)));
    return __fmul_rn(x, s);
}
__device__ __forceinline__ void lds_fence() {   // in-wave LDS round-trip ordering
    __builtin_amdgcn_wave_barrier();
    __threadfence_block();
    __builtin_amdgcn_wave_barrier();
}
__device__ __forceinline__ u64 shfl_down_u64(u64 v, int off) {
    unsigned lo = (unsigned)v, hi = (unsigned)(v >> 32);
    lo = __shfl_down(lo, off);
    hi = __shfl_down(hi, off);
    return (((u64)hi) << 32) | lo;
}
// monotone float->uint mapping (order-preserving incl. negatives)
__device__ __forceinline__ unsigned fmap(float g) {
    unsigned u = __float_as_uint(g);
    unsigned m = (unsigned)(((int)u) >> 31) | 0x80000000u;
    return u ^ m;
}
__device__ __forceinline__ float funmap(unsigned sb) {
    unsigned u = (sb & 0x80000000u) ? (sb ^ 0x80000000u) : ~sb;
    return __uint_as_float(u);
}

// ---- wave-aggregated LDS list append (1 atomic per wave per ballot) ----
__device__ __forceinline__ void append_agg(unsigned* list, int* counter, int cap, unsigned val) {
    u64 m = __ballot(1);
    int lane = (int)(threadIdx.x & 63);
    int ldr = (int)__builtin_ctzll(m);
    int pfx = (int)__builtin_popcountll(m & ((1ull << lane) - 1ull));
    int base = 0;
    if (lane == ldr) base = atomicAdd(counter, (int)__builtin_popcountll(m));
    base = __builtin_amdgcn_readfirstlane(base);
    int idx = base + pfx;
    if (idx < cap) list[idx] = val;
}

// exact-reference appr test + gap key for a near pair (d2 < D2GATE)
__device__ __forceinline__ u64 ball_key(const float4* ps, int i, int j,
                                        float dx, float dy, float d2,
                                        unsigned id, float rsum) {
    float4 A = ps[i], B = ps[j];
    float p1 = __fmul_rn(__fsub_rn(B.z, A.z), dx);
    float p2 = __fmul_rn(__fsub_rn(B.w, A.w), dy);
    float dot = __fadd_rn(p1, p2);
    float mag = __fadd_rn(fabsf(p1), fabsf(p2));
    bool appr;
    if (fabsf(dot) < __fmul_rn(1e-5f, mag)) {
        float dist = __fsqrt_rn(d2);
        float den = __fadd_rn(dist, 1e-8f);
        float ab = __fadd_rn(__fmul_rn(__fsub_rn(B.z, A.z), __fdiv_rn(dx, den)),
                             __fmul_rn(__fsub_rn(B.w, A.w), __fdiv_rn(dy, den)));
        appr = ab < 0.0f;
    } else {
        appr = dot < 0.0f;
    }
    if (!appr) return ~0ull;
    float gap = __fsub_rn(__fsqrt_rn(d2), rsum);
    return (((u64)fmap(gap)) << 17) | id;     // type bit 16 = 0 (ball)
}

__device__ void load_weights(float* w1, float* b1s, float* w2, float* b2s, float* w3, float* b3s,
                             const void* W1, const void* B1, const void* W2, const void* B2,
                             const void* W3, const void* B3, int bf, int tid, int nthr) {
    for (int k = tid; k < HID * 2; k += nthr) w1[k] = rdin(W1, k, bf);
    for (int k = tid; k < HID; k += nthr) {
        b1s[k] = rdin(B1, k, bf);
        b2s[k] = rdin(B2, k, bf);
        w3[k]  = rdin(W3, k, bf);
    }
    for (int k = tid; k < HID * HID; k += nthr) {
        int m = k >> 6, c = k & 63;
        w2[m * W2S + c] = rdin(W2, k, bf);
    }
    if (tid == 0) b3s[0] = rdin(B3, 0, bf);
}

// ---------------- dtype sniffer ----------------
__global__ void sniff_kernel(const unsigned short* st, int* ws) {
    __shared__ int ev;
    if (threadIdx.x == 0) ev = 0;
    __syncthreads();
    unsigned short u = st[threadIdx.x];
    int e = (u >> 7) & 0xFF;
    if (e >= 0x85) atomicOr(&ev, 1);
    __syncthreads();
    if (threadIdx.x == 0) ws[0] = ev ? 0 : 1;   // 1 = bf16, 0 = fp32
}

// ---------------- output row 0 = initial state (bit copy) ----------------
__global__ void row0_kernel(const void* in, void* out, const int* ws) {
    int idx = blockIdx.x * blockDim.x + threadIdx.x;
    if (ws[0]) ((unsigned short*)out)[idx] = ((const unsigned short*)in)[idx];
    else       ((float*)out)[idx] = ((const float*)in)[idx];
}

// ------- redundant-producer, wave0-decision, persistent-candidate event loop -------
__global__ __launch_bounds__(NTHR, 1) void sim_kernel(
    const void* in_state, const void* in_rad,
    const void* inW1, const void* inB1, const void* inW2, const void* inB2,
    const void* inW3, const void* inB3, const void* in_dt, const int* in_nsteps,
    void* out, const int* ws) {
    __shared__ float4 ps0[NB];          // batch-0 sim (decision state)
    __shared__ float4 psb[NB];          // own-batch sim
    __shared__ float2 pos2[NB];         // mirror of ps0.xy (SoA for cheap d2 gathers)
    __shared__ float rad[NB];
    __shared__ float w1[HID * 2], b1s[HID], w2[HID * W2S], b2s[HID], w3s[HID], b3s[1];
    __shared__ float sc0[132], scb[132];      // [4..67] h1, [68..131] h2
    __shared__ u64 redK[8];
    __shared__ float redF[4];
    __shared__ unsigned cand[CAND_MAX];
    __shared__ int candN;
    __shared__ int dI[4];
    __shared__ float dF[4];
    __shared__ int candF;
    __shared__ int rebF;               // rebuild flag for the NEXT step

    int tid = threadIdx.x;
    int b = blockIdx.x;
    int bf = ws[0];

    if (tid < NB) {
        int base0 = tid * 4;
        float4 P;
        P.x = rdin(in_state, base0 + 0, bf);
        P.y = rdin(in_state, base0 + 1, bf);
        P.z = rdin(in_state, base0 + 2, bf);
        P.w = rdin(in_state, base0 + 3, bf);
        ps0[tid] = P;
        float2 p2v; p2v.x = P.x; p2v.y = P.y;
        pos2[tid] = p2v;
        int baseb = (b * NB + tid) * 4;
        float4 Q;
        Q.x = rdin(in_state, baseb + 0, bf);
        Q.y = rdin(in_state, baseb + 1, bf);
        Q.z = rdin(in_state, baseb + 2, bf);
        Q.w = rdin(in_state, baseb + 3, bf);
        psb[tid] = Q;
        rad[tid] = rdin(in_rad, tid, bf);
        float m2 = P.z * P.z + P.w * P.w;
        #pragma unroll
        for (int off = 32; off; off >>= 1) m2 = fmaxf(m2, __shfl_down(m2, off));
        if ((tid & 63) == 0) redF[tid >> 6] = m2;
    }
    load_weights(w1, b1s, w2, b2s, w3s, b3s, inW1, inB1, inW2, inB2, inW3, inB3, bf, tid, NTHR);
    if (tid == 0) { candN = 0; candF = 0; rebF = 1; }

    float dtv = rdin(in_dt, 0, bf);
    int NS = in_nsteps[0]; if (NS > MAXSTEPS) NS = MAXSTEPS; if (NS < 0) NS = 0;

    // static tile assignment: thread t owns tiles t and t+NTHR (6x6 each)
    int i0a = -1, j0a = 0, i0b = -1, j0b = 0;
    {
        int T = tid;
        if (T < NTILES) {
            int rem = T, r = 0;
            while (rem >= NT - r) { rem -= NT - r; r++; }
            i0a = r * 6; j0a = (r + rem) * 6;
        }
        T = tid + NTHR;
        if (T < NTILES) {
            int rem = T, r = 0;
            while (rem >= NT - r) { rem -= NT - r; r++; }
            i0b = r * 6; j0b = (r + rem) * 6;
        }
    }
    __syncthreads();
    float rsum = __fadd_rn(rad[0], rad[0]);        // radii uniform

    float thB = __fadd_rn(__fadd_rn(rsum, 0.05f), CMARGIN);
    float th2B = __fmul_rn(thB, thB);

    int nc = 0;
    bool candOvf = false;
    // wave-0 persistent budget state
    float used = 1e30f, vcap = 0.0f;

    for (int s = 0; s < NS; s++) {
        int rebuild = rebF;
        float t_s = __fmul_rn((float)s, dtv);
        float t_e = __fadd_rn(t_s, dtv);
        float t_c = t_s;
        if (tid < 64) {
            if (rebuild) {
                vcap = sqrtf(fmaxf(fmaxf(redF[0], redF[1]), fmaxf(redF[2], redF[3])));
                used = 0.0f;
            }
            used = __fadd_rn(used, __fmul_rn(__fmul_rn(2.0f, dtv), vcap));
            if (tid == 0 && rebuild) candF = 0;
        }

        for (int e = 0; e < MAXEV; e++) {
            // ---------- detect phase (all 512 threads) ----------
            u64 kC = ~0ull;
            bool fullscan = (e == 0) ? (rebuild != 0) : (candF != 0);
            bool doAppend = (e == 0) && rebuild;
            if (fullscan) {
                #pragma unroll
                for (int tt = 0; tt < 2; tt++) {
                    int I0 = tt ? i0b : i0a;
                    int J0 = tt ? j0b : j0a;
                    if (I0 < 0) continue;
                    float2 Pi[6], Pj[6];
                    #pragma unroll
                    for (int a = 0; a < 6; a++) {
                        int ii = I0 + a; ii = ii < NB ? ii : NB - 1;
                        int jj = J0 + a; jj = jj < NB ? jj : NB - 1;
                        Pi[a] = pos2[ii]; Pj[a] = pos2[jj];
                    }
                    #pragma unroll
                    for (int a = 0; a < 6; a++) {
                        int i = I0 + a;
                        #pragma unroll
                        for (int bb = 0; bb < 6; bb++) {
                            int j = J0 + bb;
                            bool ok = (i < NB) && (j < NB) && (j > i);
                            float dx = __fsub_rn(Pj[bb].x, Pi[a].x);
                            float dy = __fsub_rn(Pj[bb].y, Pi[a].y);
                            float d2 = __fadd_rn(__fmul_rn(dx, dx), __fmul_rn(dy, dy));
                            unsigned id = (unsigned)((i << 8) | j);
                            if (doAppend && ok && d2 < th2B)
                                append_agg(cand, &candN, CAND_MAX, id);
                            if (ok && d2 < D2GATE) {
                                u64 key = ball_key(ps0, i, j, dx, dy, d2, id, rsum);
                                kC = key < kC ? key : kC;
                            }
                        }
                    }
                }
            } else {
                for (int c = tid; c < nc; c += NTHR) {
                    unsigned id = cand[c];
                    int i = (int)(id >> 8), j = (int)(id & 255u);
                    float2 A = pos2[i], B = pos2[j];
                    float dx = __fsub_rn(B.x, A.x), dy = __fsub_rn(B.y, A.y);
                    float d2 = __fadd_rn(__fmul_rn(dx, dx), __fmul_rn(dy, dy));
                    if (d2 < D2GATE) {
                        u64 key = ball_key(ps0, i, j, dx, dy, d2, id, rsum);
                        kC = key < kC ? key : kC;
                    }
                }
            }
            {   // wall candidates: thread = (wpair<<8)|ball; each does 2 walls
                int ball = tid & 255, wsel = tid >> 8;
                float4 P = ps0[ball]; float r = rad[ball];
                #pragma unroll
                for (int q = 0; q < 2; q++) {
                    int w = wsel * 2 + q;
                    float g; bool valid;
                    if (w == 0)      { g = __fsub_rn(P.x, r); valid = P.z < 0.0f; }
                    else if (w == 1) { g = __fsub_rn(__fsub_rn(10.0f, P.x), r); valid = P.z > 0.0f; }
                    else if (w == 2) { g = __fsub_rn(P.y, r); valid = P.w < 0.0f; }
                    else             { g = __fsub_rn(__fsub_rn(10.0f, P.y), r); valid = P.w > 0.0f; }
                    if (valid) {
                        u64 key = (((u64)fmap(g)) << 17) | 0x10000u | (unsigned)(ball * 4 + w);
                        kC = key < kC ? key : kC;
                    }
                }
            }
            #pragma unroll
            for (int off = 32; off; off >>= 1) {
                u64 o = shfl_down_u64(kC, off);
                kC = o < kC ? o : kC;
            }
            if ((tid & 63) == 0) redK[tid >> 6] = kC;
            __syncthreads();                                     // B1

            if (e == 0 && rebuild) {
                int ct = candN;
                candOvf = ct > CAND_MAX;
                nc = candOvf ? CAND_MAX : ct;
            }

            // ---------- decision: wave 0 only; sim0 geometry kept in registers ----------
            float g_nx = 0, g_ny = 0, g_dist = 0, g_app = 0;
            float4 gA, gB;
            if (tid < 64) {
                u64 m = redK[0];
                #pragma unroll
                for (int q = 1; q < 8; q++) m = redK[q] < m ? redK[q] : m;
                int code_ = 0; float dteB_ = 0.0f, tcn_ = t_c;
                int ei_ = 0, ej_ = 0;
                if (m != ~0ull) {
                    bool is_ball = ((m >> 16) & 1ull) == 0;
                    unsigned id = (unsigned)(m & 0xFFFFull);
                    float gap = funmap((unsigned)(m >> 17));
                    int pi = (int)(id >> 8), pj = (int)(id & 255u);
                    int wb = (int)(id >> 2), ww = (int)(id & 3u);
                    ei_ = is_ball ? pi : wb;
                    ej_ = is_ball ? pj : ww;
                    if (!(gap > 0.05f)) {
                        float app;
                        if (is_ball) {
                            float4 A = ps0[pi], B = ps0[pj];
                            float dx = __fsub_rn(B.x, A.x), dy = __fsub_rn(B.y, A.y);
                            float nrm = __fsqrt_rn(__fadd_rn(__fmul_rn(dx, dx), __fmul_rn(dy, dy)));
                            float dvx = __fsub_rn(B.z, A.z), dvy = __fsub_rn(B.w, A.w);
                            app = -__fadd_rn(__fdiv_rn(__fmul_rn(dvx, dx), nrm),
                                             __fdiv_rn(__fmul_rn(dvy, dy), nrm));
                        } else {
                            float4 Wb = ps0[wb];
                            app = fabsf(fmaxf(Wb.z, Wb.w));
                        }
                        float t_ev = __fadd_rn(t_c, __fdiv_rn(gap, fmaxf(app, 1e-6f)));
                        if (gap <= 0.0f) {
                            code_ = is_ball ? 1 : 3;
                        } else if (app > 1e-6f && t_ev < t_e) {
                            code_ = is_ball ? 2 : 4;
                            dteB_ = (t_ev > __fadd_rn(t_c, 1e-10f)) ? __fsub_rn(t_ev, t_c) : 0.0f;
                            tcn_ = t_ev;
                        }
                    }
                }
                if (tid == 0) {
                    dI[0] = code_; dI[1] = ei_; dI[2] = ej_;
                    dF[0] = dteB_; dF[1] = tcn_;
                }
                if (code_ != 0 && code_ <= 2) {
                    float4 A = ps0[ei_], B = ps0[ej_];
                    if (code_ == 2) {
                        A.x = __fadd_rn(A.x, __fmul_rn(A.z, dteB_));
                        A.y = __fadd_rn(A.y, __fmul_rn(A.w, dteB_));
                        B.x = __fadd_rn(B.x, __fmul_rn(B.z, dteB_));
                        B.y = __fadd_rn(B.y, __fmul_rn(B.w, dteB_));
                    }
                    gA = A; gB = B;
                    float dx = __fsub_rn(B.x, A.x), dy = __fsub_rn(B.y, A.y);
                    float nrm = __fsqrt_rn(__fadd_rn(__fmul_rn(dx, dx), __fmul_rn(dy, dy)));
                    float dist = fmaxf(nrm, 1e-8f);
                    g_nx = __fdiv_rn(dx, dist); g_ny = __fdiv_rn(dy, dist);
                    g_dist = dist;
                    float dvx = __fsub_rn(B.z, A.z), dvy = __fsub_rn(B.w, A.w);
                    g_app = __fadd_rn(__fmul_rn(dvx, g_nx), __fmul_rn(dvy, g_ny));
                }
            }
            __syncthreads();                                     // B1b (publish)

            int code = dI[0];
            if (code == 0) break;
            int ei = dI[1], ejw = dI[2];
            float dteB = dF[0];
            t_c = dF[1];
            bool integ = (code == 2) || (code == 4);

            // ---------- apply phase P2 (one barrier at end) ----------
            if (code <= 2) {
                if (tid < 64) {
                    // wave 0: sim0 MLP from registers, in-wave LDS round-trips
                    float a = __fadd_rn(__fadd_rn(__fmul_rn(g_dist, w1[2 * tid]),
                                                  __fmul_rn(g_app, w1[2 * tid + 1])), b1s[tid]);
                    sc0[4 + tid] = silu_f(a);
                    lds_fence();
                    float acc = 0.0f;
                    const float* row = &w2[tid * W2S];
                    #pragma unroll 8
                    for (int k = 0; k < HID; k++) acc = __fadd_rn(acc, __fmul_rn(sc0[4 + k], row[k]));
                    acc = __fadd_rn(acc, b2s[tid]);
                    sc0[68 + tid] = silu_f(acc);
                    lds_fence();
                    float acc3 = 0.0f;
                    #pragma unroll 8
                    for (int k = 0; k < HID; k++)
                        acc3 = __fadd_rn(acc3, __fmul_rn(sc0[68 + k], w3s[k]));
                    float impv = __fadd_rn(acc3, b3s[0]);
                    float ix = __fmul_rn(impv, g_nx), iy = __fmul_rn(impv, g_ny);
                    float nAz = __fadd_rn(gA.z, ix),  nAw = __fadd_rn(gA.w, iy);
                    float nBz = __fadd_rn(gB.z, -ix), nBw = __fadd_rn(gB.w, -iy);
                    if (tid == 0) {
                        float4 outA; outA.x = gA.x; outA.y = gA.y; outA.z = nAz; outA.w = nAw;
                        float4 outB; outB.x = gB.x; outB.y = gB.y; outB.z = nBz; outB.w = nBw;
                        ps0[ei] = outA; ps0[ejw] = outB;
                        float2 pa; pa.x = gA.x; pa.y = gA.y; pos2[ei] = pa;
                        float2 pb; pb.x = gB.x; pb.y = gB.y; pos2[ejw] = pb;
                    }
                    float s1 = sqrtf(nAz * nAz + nAw * nAw);
                    float s2 = sqrtf(nBz * nBz + nBw * nBw);
                    float nv = fmaxf(s1, s2);
                    used = __fadd_rn(used, __fmul_rn(__fmul_rn(2.0f, dtv),
                                                     fmaxf(__fsub_rn(nv, vcap), 0.0f)));
                    vcap = fmaxf(vcap, nv);
                    int nf = (candOvf || (__fadd_rn(used, 1e-3f) > CMARGIN)) ? 1 : 0;
                    if (tid == 0) candF = nf;
                } else if (tid < 128) {
                    // wave 1: simb full apply (geometry + MLP), in-wave
                    int lane = tid - 64;
                    float4 A = psb[ei], B = psb[ejw];
                    if (integ) {
                        A.x = __fadd_rn(A.x, __fmul_rn(A.z, dteB));
                        A.y = __fadd_rn(A.y, __fmul_rn(A.w, dteB));
                        B.x = __fadd_rn(B.x, __fmul_rn(B.z, dteB));
                        B.y = __fadd_rn(B.y, __fmul_rn(B.w, dteB));
                    }
                    float dx = __fsub_rn(B.x, A.x), dy = __fsub_rn(B.y, A.y);
                    float nrm = __fsqrt_rn(__fadd_rn(__fmul_rn(dx, dx), __fmul_rn(dy, dy)));
                    float dist = fmaxf(nrm, 1e-8f);
                    float nx = __fdiv_rn(dx, dist), ny = __fdiv_rn(dy, dist);
                    float dvx = __fsub_rn(B.z, A.z), dvy = __fsub_rn(B.w, A.w);
                    float app2 = __fadd_rn(__fmul_rn(dvx, nx), __fmul_rn(dvy, ny));
                    float a = __fadd_rn(__fadd_rn(__fmul_rn(dist, w1[2 * lane]),
                                                  __fmul_rn(app2, w1[2 * lane + 1])), b1s[lane]);
                    scb[4 + lane] = silu_f(a);
                    lds_fence();
                    float acc = 0.0f;
                    const float* row = &w2[lane * W2S];
                    #pragma unroll 8
                    for (int k = 0; k < HID; k++) acc = __fadd_rn(acc, __fmul_rn(scb[4 + k], row[k]));
                    acc = __fadd_rn(acc, b2s[lane]);
                    scb[68 + lane] = silu_f(acc);
                    lds_fence();
                    float acc3 = 0.0f;
                    #pragma unroll 8
                    for (int k = 0; k < HID; k++)
                        acc3 = __fadd_rn(acc3, __fmul_rn(scb[68 + k], w3s[k]));
                    float impv = __fadd_rn(acc3, b3s[0]);
                    if (lane == 0) {
                        float ix = __fmul_rn(impv, nx), iy = __fmul_rn(impv, ny);
                        float4 outA; outA.x = A.x; outA.y = A.y;
                        outA.z = __fadd_rn(A.z, ix);  outA.w = __fadd_rn(A.w, iy);
                        float4 outB; outB.x = B.x; outB.y = B.y;
                        outB.z = __fadd_rn(B.z, -ix); outB.w = __fadd_rn(B.w, -iy);
                        psb[ei] = outA; psb[ejw] = outB;
                    }
                } else if (tid < 384) {
                    int t = tid - 128;
                    if (integ && t != ei && t != ejw) {
                        float4 P = ps0[t];
                        P.x = __fadd_rn(P.x, __fmul_rn(P.z, dteB));
                        P.y = __fadd_rn(P.y, __fmul_rn(P.w, dteB));
                        ps0[t] = P;
                        float2 pp; pp.x = P.x; pp.y = P.y; pos2[t] = pp;
                    }
                } else {
                    #pragma unroll
                    for (int q = 0; q < 2; q++) {
                        int t = (tid - 384) + q * 128;
                        if (integ && t != ei && t != ejw) {
                            float4 Q = psb[t];
                            Q.x = __fadd_rn(Q.x, __fmul_rn(Q.z, dteB));
                            Q.y = __fadd_rn(Q.y, __fmul_rn(Q.w, dteB));
                            psb[t] = Q;
                        }
                    }
                }
                __syncthreads();                                 // P2 end
            } else {
                // ---------- wall event ----------
                const float wnx[4] = {1.f, -1.f, 0.f, 0.f};
                const float wny[4] = {0.f, 0.f, 1.f, -1.f};
                const float wpv[4] = {0.f, -10.f, 0.f, -10.f};
                int w = ejw;
                if (tid < 64) {
                    float4 P = ps0[ei];
                    if (integ) {
                        P.x = __fadd_rn(P.x, __fmul_rn(P.z, dteB));
                        P.y = __fadd_rn(P.y, __fmul_rn(P.w, dteB));
                    }
                    float vn = __fadd_rn(__fmul_rn(P.z, wnx[w]), __fmul_rn(P.w, wny[w]));
                    float t2 = __fmul_rn(2.0f, vn);
                    float nvx = __fsub_rn(P.z, __fmul_rn(t2, wnx[w]));
                    float nvy = __fsub_rn(P.w, __fmul_rn(t2, wny[w]));
                    float pn = __fadd_rn(__fmul_rn(P.x, wnx[w]), __fmul_rn(P.y, wny[w]));
                    float pen = fmaxf(__fsub_rn(__fadd_rn(wpv[w], rad[ei]), pn), 0.0f);
                    float4 nP;
                    nP.x = __fadd_rn(P.x, __fmul_rn(pen, wnx[w]));
                    nP.y = __fadd_rn(P.y, __fmul_rn(pen, wny[w]));
                    nP.z = nvx; nP.w = nvy;
                    used = __fadd_rn(used, pen);
                    int nf = (candOvf || (__fadd_rn(used, 1e-3f) > CMARGIN)) ? 1 : 0;
                    if (tid == 0) {
                        ps0[ei] = nP;
                        float2 pp; pp.x = nP.x; pp.y = nP.y; pos2[ei] = pp;
                        candF = nf;
                    }
                } else if (tid < 128) {
                    if (tid == 64) {
                        float4 P = psb[ei];
                        if (integ) {
                            P.x = __fadd_rn(P.x, __fmul_rn(P.z, dteB));
                            P.y = __fadd_rn(P.y, __fmul_rn(P.w, dteB));
                        }
                        float vn = __fadd_rn(__fmul_rn(P.z, wnx[w]), __fmul_rn(P.w, wny[w]));
                        float t2 = __fmul_rn(2.0f, vn);
                        float nvx = __fsub_rn(P.z, __fmul_rn(t2, wnx[w]));
                        float nvy = __fsub_rn(P.w, __fmul_rn(t2, wny[w]));
                        float pn = __fadd_rn(__fmul_rn(P.x, wnx[w]), __fmul_rn(P.y, wny[w]));
                        float pen = fmaxf(__fsub_rn(__fadd_rn(wpv[w], rad[ei]), pn), 0.0f);
                        float4 nP;
                        nP.x = __fadd_rn(P.x, __fmul_rn(pen, wnx[w]));
                        nP.y = __fadd_rn(P.y, __fmul_rn(pen, wny[w]));
                        nP.z = nvx; nP.w = nvy;
                        psb[ei] = nP;
                    }
                } else if (tid < 384) {
                    int t = tid - 128;
                    if (integ && t != ei) {
                        float4 P = ps0[t];
                        P.x = __fadd_rn(P.x, __fmul_rn(P.z, dteB));
                        P.y = __fadd_rn(P.y, __fmul_rn(P.w, dteB));
                        ps0[t] = P;
                        float2 pp; pp.x = P.x; pp.y = P.y; pos2[t] = pp;
                    }
                } else {
                    #pragma unroll
                    for (int q = 0; q < 2; q++) {
                        int t = (tid - 384) + q * 128;
                        if (integ && t != ei) {
                            float4 Q = psb[t];
                            Q.x = __fadd_rn(Q.x, __fmul_rn(Q.z, dteB));
                            Q.y = __fadd_rn(Q.y, __fmul_rn(Q.w, dteB));
                            psb[t] = Q;
                        }
                    }
                }
                __syncthreads();                                 // P2 end
            }
        }

        // ---------- step end: final integrate + vmax + store (fused) ----------
        float fd = (t_e > __fadd_rn(t_c, 1e-10f)) ? __fsub_rn(t_e, t_c) : 0.0f;
        if (tid < NB) {
            float4 P = ps0[tid];
            P.x = __fadd_rn(P.x, __fmul_rn(P.z, fd));
            P.y = __fadd_rn(P.y, __fmul_rn(P.w, fd));
            ps0[tid] = P;
            float2 pp; pp.x = P.x; pp.y = P.y; pos2[tid] = pp;
            float m2 = P.z * P.z + P.w * P.w;
            #pragma unroll
            for (int off = 32; off; off >>= 1) m2 = fmaxf(m2, __shfl_down(m2, off));
            if ((tid & 63) == 0) redF[tid >> 6] = m2;
            if (tid == 0) {
                candN = 0;
                float usedNext = __fadd_rn(used, __fmul_rn(__fmul_rn(2.0f, dtv), vcap));
                rebF = (candOvf || (__fadd_rn(usedNext, 1e-3f) > CMARGIN)) ? 1 : 0;
            }
        } else {
            int t = tid - NB;
            float4 Q = psb[t];
            Q.x = __fadd_rn(Q.x, __fmul_rn(Q.z, fd));
            Q.y = __fadd_rn(Q.y, __fmul_rn(Q.w, fd));
            psb[t] = Q;
            long long base = ((long long)(s + 1) * NBATCH + b) * (NB * 4);
            if (bf) {
                ushort4 v;
                v.x = f2bf(Q.x); v.y = f2bf(Q.y); v.z = f2bf(Q.z); v.w = f2bf(Q.w);
                ((ushort4*)((unsigned short*)out + base))[t] = v;
            } else {
                ((float4*)((float*)out + base))[t] = Q;
            }
        }
        __syncthreads();
    }
}

extern "C" void kernel_launch(void* const* d_in, const int* in_sizes, int n_in,
                              void* d_out, int out_size, void* d_ws, size_t ws_size,
                              hipStream_t stream) {
    // inputs: 0 state, 1 radii, 2 W1, 3 b1, 4 W2, 5 b2, 6 W3, 7 b3, 8 dt, 9 n_steps
    int* ws = (int*)d_ws;
    sniff_kernel<<<1, 256, 0, stream>>>((const unsigned short*)d_in[0], ws);
    row0_kernel<<<(NBATCH * NB * 4) / 256, 256, 0, stream>>>(d_in[0], d_out, ws);
    sim_kernel<<<NBATCH, NTHR, 0, stream>>>(
        d_in[0], d_in[1], d_in[2], d_in[3], d_in[4], d_in[5], d_in[6], d_in[7],
        d_in[8], (const int*)d_in[9], d_out, ws);
}